// Round 6
// baseline (917.295 us; speedup 1.0000x reference)
//
#include <hip/hip_runtime.h>

typedef unsigned short u16;
typedef __attribute__((ext_vector_type(8))) short bf16x8;
typedef __attribute__((ext_vector_type(8))) unsigned short u16x8;
typedef __attribute__((ext_vector_type(4))) float f32x4;

#define NTOK 8192
#define DDIM 1024
#define HDIM 4096
#define NEXP 8
#define NTILE 136   // 8 XCD chunks x 17 slots; >= max Sum(ceil(cnt_e/128)) = 135

typedef __attribute__((address_space(1))) const void gvoid;
typedef __attribute__((address_space(3))) void lvoid;

__device__ __forceinline__ u16 f2b(float f) {
  unsigned u = __float_as_uint(f);
  u += 0x7fffu + ((u >> 16) & 1u);   // RNE
  return (u16)(u >> 16);
}
__device__ __forceinline__ void glds16(const void* g, void* l) {
  __builtin_amdgcn_global_load_lds((gvoid*)g, (lvoid*)l, 16, 0, 0);
}

// ---------------- pre-pass: x fp32 -> bf16 ----------------------------------
__global__ void convert_x_kernel(const float* __restrict__ src, u16* __restrict__ dst) {
  size_t i = ((size_t)blockIdx.x * 256 + threadIdx.x) * 8;
  float4 a = *(const float4*)(src + i);
  float4 b = *(const float4*)(src + i + 4);
  u16x8 o;
  o[0] = f2b(a.x); o[1] = f2b(a.y); o[2] = f2b(a.z); o[3] = f2b(a.w);
  o[4] = f2b(b.x); o[5] = f2b(b.y); o[6] = f2b(b.z); o[7] = f2b(b.w);
  *(u16x8*)(dst + i) = o;
}

// ---------------- pre-pass: [R][C] fp32 -> [C][R] bf16 (per expert) ---------
__global__ void transpose_kernel(const float* __restrict__ src, u16* __restrict__ dst,
                                 int R, int C) {
  int e = blockIdx.z;
  src += (size_t)e * R * C;
  dst += (size_t)e * R * C;
  int r0 = blockIdx.y * 64, c0 = blockIdx.x * 64;
  __shared__ u16 T[64][68];   // row stride 136 B: 8B-aligned, 2-way bank alias (free)
  int t = threadIdx.x;
  int rr = t >> 4, cc = (t & 15) * 4;
#pragma unroll
  for (int i = 0; i < 4; ++i) {
    int r = i * 16 + rr;
    float4 v = *(const float4*)(src + (size_t)(r0 + r) * C + c0 + cc);
    T[cc + 0][r] = f2b(v.x);
    T[cc + 1][r] = f2b(v.y);
    T[cc + 2][r] = f2b(v.z);
    T[cc + 3][r] = f2b(v.w);
  }
  __syncthreads();
#pragma unroll
  for (int i = 0; i < 4; ++i) {
    int c = i * 16 + rr;
    ushort4 o = *(const ushort4*)&T[c][cc];
    *(ushort4*)(dst + (size_t)(c0 + c) * R + r0 + cc) = o;
  }
}

// ---------------- gating: softmax over 8 experts, top-2, bucket by expert ----
// counts_pad: expert e's counter lives at counts_pad[e*32] -> own 128B line,
// so the 16384 device atomics form 8 parallel chains instead of one.
__global__ void gate_kernel(const float* __restrict__ x, const float* __restrict__ Wg,
                            const float* __restrict__ bg, int* __restrict__ counts_pad,
                            int* __restrict__ pair_tok, float* __restrict__ pair_w,
                            int* __restrict__ tok_ep)
{
  int lane = threadIdx.x & 63;
  int wave = threadIdx.x >> 6;
  int tok = blockIdx.x * 4 + wave;
  const float* xr = x + (size_t)tok * DDIM + lane * 16;
  float acc[NEXP];
#pragma unroll
  for (int e = 0; e < NEXP; ++e) acc[e] = 0.f;
#pragma unroll
  for (int j = 0; j < 16; ++j) {
    float xf = xr[j];
    const float* wr = Wg + (size_t)(lane * 16 + j) * NEXP;
    float4 wa = *(const float4*)(wr);
    float4 wb = *(const float4*)(wr + 4);
    acc[0] = fmaf(xf, wa.x, acc[0]);
    acc[1] = fmaf(xf, wa.y, acc[1]);
    acc[2] = fmaf(xf, wa.z, acc[2]);
    acc[3] = fmaf(xf, wa.w, acc[3]);
    acc[4] = fmaf(xf, wb.x, acc[4]);
    acc[5] = fmaf(xf, wb.y, acc[5]);
    acc[6] = fmaf(xf, wb.z, acc[6]);
    acc[7] = fmaf(xf, wb.w, acc[7]);
  }
#pragma unroll
  for (int off = 32; off > 0; off >>= 1) {
#pragma unroll
    for (int e = 0; e < NEXP; ++e) acc[e] += __shfl_xor(acc[e], off, 64);
  }
  if (lane == 0) {
    float l[NEXP];
    float mx = -3.4e38f;
#pragma unroll
    for (int e = 0; e < NEXP; ++e) { l[e] = acc[e] + bg[e]; mx = fmaxf(mx, l[e]); }
    float s = 0.f;
#pragma unroll
    for (int e = 0; e < NEXP; ++e) { l[e] = __expf(l[e] - mx); s += l[e]; }
    float inv = 1.f / s;
    float v1 = -1.f; int i1 = 0;
#pragma unroll
    for (int e = 0; e < NEXP; ++e) { if (l[e] > v1) { v1 = l[e]; i1 = e; } }
    float v2 = -1.f; int i2 = 0;
#pragma unroll
    for (int e = 0; e < NEXP; ++e) { if (e != i1 && l[e] > v2) { v2 = l[e]; i2 = e; } }
    int p1 = atomicAdd(&counts_pad[i1 * 32], 1);
    pair_tok[i1 * NTOK + p1] = tok;
    pair_w[i1 * NTOK + p1] = v1 * inv;   // raw top-k softmax prob (not renormalized)
    tok_ep[2 * tok + 0] = (i1 << 16) | p1;
    int p2 = atomicAdd(&counts_pad[i2 * 32], 1);
    pair_tok[i2 * NTOK + p2] = tok;
    pair_w[i2 * NTOK + p2] = v2 * inv;
    tok_ep[2 * tok + 1] = (i2 << 16) | p2;
  }
}

// ---------------- offsets + XCD-chunked worklist (tiny, 1 thread) -----------
// Grid slot w -> expert-major tile (w%8)*17 + w/8, so XCD c (= w%8) processes
// 17 CONTIGUOUS expert-major tiles (~one expert) -> B-slab stays in its L2.
__global__ void offsets_kernel(const int* __restrict__ counts_pad, int* __restrict__ counts,
                               int* __restrict__ offsets, int* __restrict__ tile_e,
                               int* __restrict__ tile_i0, int* __restrict__ ntiles)
{
  if (threadIdx.x == 0) {
    int te[NTILE], ti[NTILE];
    int s = 0;
    for (int e = 0; e < NEXP; ++e) {
      int c = counts_pad[e * 32];
      counts[e] = c; offsets[e] = s; s += c;
    }
    int nt_ = 0;
    for (int e = 0; e < NEXP; ++e)
      for (int i0 = 0; i0 < counts[e]; i0 += 128) { te[nt_] = e; ti[nt_] = i0; nt_++; }
    for (int w = 0; w < NTILE; ++w) {
      int t = (w & 7) * 17 + (w >> 3);
      tile_e[w]  = (t < nt_) ? te[t] : -1;
      tile_i0[w] = (t < nt_) ? ti[t] : 0;
    }
    *ntiles = nt_;
  }
}

// ---------------- shared GEMM helpers (128x128 tile, BK=32, 4 waves) --------
__device__ __forceinline__ void stage4(const u16* xa0, const u16* xa1,
                                       const u16* wb0, const u16* wb1,
                                       u16* Asb, u16* Bsb, int wave, int koff) {
  glds16(xa0 + koff, Asb + wave * 512);
  glds16(xa1 + koff, Asb + 2048 + wave * 512);
  glds16(wb0 + koff, Bsb + wave * 512);
  glds16(wb1 + koff, Bsb + 2048 + wave * 512);
}

__device__ __forceinline__ void mfma_tile(const u16* Asb, const u16* Bsb,
                                          f32x4 (&acc)[4][4],
                                          int wrr, int wc, int ln, int q) {
  bf16x8 af[4], bfr[4];
#pragma unroll
  for (int mt = 0; mt < 4; ++mt)
    af[mt] = *(const bf16x8*)(Asb + (wrr + mt * 16 + ln) * 32 + q * 8);
#pragma unroll
  for (int nt = 0; nt < 4; ++nt)
    bfr[nt] = *(const bf16x8*)(Bsb + (wc + nt * 16 + ln) * 32 + q * 8);
#pragma unroll
  for (int mt = 0; mt < 4; ++mt)
#pragma unroll
    for (int nt = 0; nt < 4; ++nt)
      acc[mt][nt] = __builtin_amdgcn_mfma_f32_16x16x32_bf16(af[mt], bfr[nt], acc[mt][nt], 0, 0, 0);
}

// 3-deep counted-vmcnt K-loop (T4-lite): loads for buffer k+1/k+2 stay in
// flight across the barrier; steady-state wait is vmcnt(4), never 0.
// Race-safety: one s_barrier/iter bounds wave skew <1 iter; stage targets
// b[k+2] while readers use b[k]; lgkmcnt(0) before the barrier retires all
// ds_reads of b[k-1] before its buffer is overwritten; sched_barrier(0)
// fences compiler motion across the sync block (rule #18).
#define GEMM_LOOP(KDIM)                                                      \
  stage4(xa0, xa1, wb0, wb1, As[0], Bs[0], wave, 0);                         \
  stage4(xa0, xa1, wb0, wb1, As[1], Bs[1], wave, 32);                        \
  {                                                                          \
    int cur = 0, nx2 = 2;                                                    \
    for (int k0 = 0; k0 < (KDIM); k0 += 32) {                                \
      __builtin_amdgcn_sched_barrier(0);                                     \
      if (k0 + 32 < (KDIM))                                                  \
        asm volatile("s_waitcnt vmcnt(4) lgkmcnt(0)" ::: "memory");          \
      else                                                                   \
        asm volatile("s_waitcnt vmcnt(0) lgkmcnt(0)" ::: "memory");          \
      __builtin_amdgcn_s_barrier();                                          \
      __builtin_amdgcn_sched_barrier(0);                                     \
      if (k0 + 64 < (KDIM))                                                  \
        stage4(xa0, xa1, wb0, wb1, As[nx2], Bs[nx2], wave, k0 + 64);         \
      mfma_tile(As[cur], Bs[cur], acc, wrr, wc, ln, q);                      \
      cur = (cur == 2) ? 0 : cur + 1;                                        \
      nx2 = (nx2 == 2) ? 0 : nx2 + 1;                                        \
    }                                                                        \
  }

// ---------------- grouped GEMM1: h = relu(gather(xb) @ W1T[e]^T + b1[e]) ----
__global__ __launch_bounds__(256) void gemm1_kernel(
    const u16* __restrict__ xb, const u16* __restrict__ W1T,
    const float* __restrict__ b1, const int* __restrict__ counts,
    const int* __restrict__ offsets, const int* __restrict__ ntiles,
    const int* __restrict__ tile_e, const int* __restrict__ tile_i0,
    const int* __restrict__ pair_tok, u16* __restrict__ h, int hp, int p0)
{
  int bx = blockIdx.x;
  int e = tile_e[bx];
  if (e < 0) return;
  int i0 = tile_i0[bx];
  int cnt = counts[e];
  int n0 = blockIdx.y * 128;

  __shared__ __align__(16) u16 As[3][4096];
  __shared__ __align__(16) u16 Bs[3][4096];

  int t = threadIdx.x;
  int lane = t & 63;
  int wave = t >> 6;
  int rlim = cnt - i0;
  int rl = rlim - 1;

  const int* tokp = pair_tok + e * NTOK + i0;
  int arow = t >> 2;
  int c8 = (t & 3) * 8;
  const u16* xa0 = xb + (size_t)tokp[min(arow, rl)] * DDIM + c8;
  const u16* xa1 = xb + (size_t)tokp[min(arow + 64, rl)] * DDIM + c8;
  const u16* wb0 = W1T + (size_t)e * HDIM * DDIM + (size_t)(p0 + n0 + arow) * DDIM + c8;
  const u16* wb1 = wb0 + (size_t)64 * DDIM;

  f32x4 acc[4][4] = {};
  int wrr = (wave >> 1) * 64;
  int wc = (wave & 1) * 64;
  int ln = lane & 15;
  int q = lane >> 4;

  GEMM_LOOP(DDIM);

  int ob = offsets[e];
  float bb[4];
#pragma unroll
  for (int nt = 0; nt < 4; ++nt)
    bb[nt] = b1[(size_t)e * HDIM + p0 + n0 + wc + nt * 16 + ln];
  size_t hbase = (size_t)(ob + i0) * hp + n0 + wc;
#pragma unroll
  for (int mt = 0; mt < 4; ++mt) {
#pragma unroll
    for (int r = 0; r < 4; ++r) {
      int row = wrr + mt * 16 + q * 4 + r;
      if (row < rlim) {
        u16* hrow = h + hbase + (size_t)row * hp;
#pragma unroll
        for (int nt = 0; nt < 4; ++nt) {
          float v = acc[mt][nt][r] + bb[nt];
          hrow[nt * 16 + ln] = f2b(fmaxf(v, 0.f));
        }
      }
    }
  }
}

// ---------------- grouped GEMM2: y[slot] (+)= h @ W2T[e]^T (+ b2[e]) --------
__global__ __launch_bounds__(256) void gemm2_kernel(
    const u16* __restrict__ h, const u16* __restrict__ W2T,
    const float* __restrict__ b2v, const int* __restrict__ counts,
    const int* __restrict__ offsets, const int* __restrict__ ntiles,
    const int* __restrict__ tile_e, const int* __restrict__ tile_i0,
    float* __restrict__ y, int hp, int p0, int first)
{
  int bx = blockIdx.x;
  int e = tile_e[bx];
  if (e < 0) return;
  int i0 = tile_i0[bx];
  int cnt = counts[e];
  int n0 = blockIdx.y * 128;

  __shared__ __align__(16) u16 As[3][4096];
  __shared__ __align__(16) u16 Bs[3][4096];

  int t = threadIdx.x;
  int lane = t & 63;
  int wave = t >> 6;
  int rlim = cnt - i0;
  int rl = rlim - 1;
  int rbase = offsets[e] + i0;

  int arow = t >> 2;
  int c8 = (t & 3) * 8;
  const u16* xa0 = h + (size_t)(rbase + min(arow, rl)) * hp + c8;
  const u16* xa1 = h + (size_t)(rbase + min(arow + 64, rl)) * hp + c8;
  const u16* wb0 = W2T + (size_t)e * DDIM * HDIM + (size_t)(n0 + arow) * HDIM + p0 + c8;
  const u16* wb1 = wb0 + (size_t)64 * HDIM;

  f32x4 acc[4][4] = {};
  int wrr = (wave >> 1) * 64;
  int wc = (wave & 1) * 64;
  int ln = lane & 15;
  int q = lane >> 4;

  GEMM_LOOP(hp);

  float bb[4];
#pragma unroll
  for (int nt = 0; nt < 4; ++nt)
    bb[nt] = first ? b2v[(size_t)e * DDIM + n0 + wc + nt * 16 + ln] : 0.f;
#pragma unroll
  for (int mt = 0; mt < 4; ++mt) {
#pragma unroll
    for (int r = 0; r < 4; ++r) {
      int row = wrr + mt * 16 + q * 4 + r;
      if (row < rlim) {
        float* yr = y + (size_t)(rbase + row) * DDIM + n0 + wc;
#pragma unroll
        for (int nt = 0; nt < 4; ++nt) {
          float v = acc[mt][nt][r] + bb[nt];
          if (first) yr[nt * 16 + ln] = v;
          else       yr[nt * 16 + ln] += v;
        }
      }
    }
  }
}

// ---------------- combine: out[tok] = w1*y[slot1] + w2*y[slot2] -------------
__global__ __launch_bounds__(256) void combine_kernel(
    const float* __restrict__ y, const int* __restrict__ tok_ep,
    const float* __restrict__ pair_w, const int* __restrict__ offsets,
    float* __restrict__ out)
{
  int tok = blockIdx.x;
  int ep1 = tok_ep[2 * tok + 0];
  int ep2 = tok_ep[2 * tok + 1];
  int e1 = ep1 >> 16, p1 = ep1 & 0xffff;
  int e2 = ep2 >> 16, p2 = ep2 & 0xffff;
  float w1 = pair_w[e1 * NTOK + p1];
  float w2 = pair_w[e2 * NTOK + p2];
  const float* r1 = y + (size_t)(offsets[e1] + p1) * DDIM;
  const float* r2 = y + (size_t)(offsets[e2] + p2) * DDIM;
  int c = threadIdx.x * 4;
  float4 a = *(const float4*)(r1 + c);
  float4 b = *(const float4*)(r2 + c);
  float4 o;
  o.x = w1 * a.x + w2 * b.x;
  o.y = w1 * a.y + w2 * b.y;
  o.z = w1 * a.z + w2 * b.z;
  o.w = w1 * a.w + w2 * b.w;
  *(float4*)(out + (size_t)tok * DDIM + c) = o;
}

// ---------------- host launch ------------------------------------------------
extern "C" void kernel_launch(void* const* d_in, const int* in_sizes, int n_in,
                              void* d_out, int out_size, void* d_ws, size_t ws_size,
                              hipStream_t stream)
{
  const float* x  = (const float*)d_in[0];
  const float* Wg = (const float*)d_in[1];
  const float* bg = (const float*)d_in[2];
  const float* W1 = (const float*)d_in[3];
  const float* b1 = (const float*)d_in[4];
  const float* W2 = (const float*)d_in[5];
  const float* b2 = (const float*)d_in[6];
  float* out = (float*)d_out;

  char* ws = (char*)d_ws;
  int*   counts_pad = (int*)(ws + 0);                      // 8 counters, 128B apart
  int*   counts     = (int*)(ws + 1024);
  int*   offsets    = (int*)(ws + 1056);
  int*   ntiles     = (int*)(ws + 1088);
  int*   tile_e     = (int*)(ws + 1152);                   // NTILE entries
  int*   tile_i0    = (int*)(ws + 2176);
  int*   tok_ep     = (int*)(ws + 4096);                   // 64 KiB
  int*   pair_tok   = (int*)(ws + 69632);                  // 256 KiB
  float* pair_w     = (float*)(ws + 331776);               // 256 KiB
  u16*   xb  = (u16*)(ws + 593920);                                // 16.78 MB
  u16*   W1T = (u16*)(ws + 593920 + 16777216);                     // 67.1 MB
  u16*   W2T = (u16*)(ws + 593920 + 16777216 + 67108864);          // 67.1 MB
  float* yb  = (float*)(ws + 593920 + 16777216 + 2 * (size_t)67108864);
  u16*   hbuf = (u16*)(ws + 593920 + 16777216 + 3 * (size_t)67108864);
  size_t used_base = 593920 + 16777216 + 3 * (size_t)67108864;

  // largest H-phase width whose h buffer ((16384+128) rows x hp bf16) fits in ws
  int hp = 256;
  const int cands[5] = {4096, 2048, 1024, 512, 256};
  for (int ci = 0; ci < 5; ++ci) {
    if (used_base + (size_t)16512 * cands[ci] * 2 <= ws_size) { hp = cands[ci]; break; }
  }

  hipMemsetAsync(counts_pad, 0, 1024, stream);
  convert_x_kernel<<<NTOK * DDIM / 2048, 256, 0, stream>>>(x, xb);
  // W1 [E][D][H] -> W1T [E][H][D]
  transpose_kernel<<<dim3(HDIM / 64, DDIM / 64, NEXP), 256, 0, stream>>>(W1, W1T, DDIM, HDIM);
  // W2 [E][H][D] -> W2T [E][D][H]
  transpose_kernel<<<dim3(DDIM / 64, HDIM / 64, NEXP), 256, 0, stream>>>(W2, W2T, HDIM, DDIM);
  gate_kernel<<<NTOK / 4, 256, 0, stream>>>(x, Wg, bg, counts_pad, pair_tok, pair_w, tok_ep);
  offsets_kernel<<<1, 64, 0, stream>>>(counts_pad, counts, offsets, tile_e, tile_i0, ntiles);
  for (int p0 = 0; p0 < HDIM; p0 += hp) {
    gemm1_kernel<<<dim3(NTILE, hp / 128), 256, 0, stream>>>(
        xb, W1T, b1, counts, offsets, ntiles, tile_e, tile_i0, pair_tok, hbuf, hp, p0);
    gemm2_kernel<<<dim3(NTILE, DDIM / 128), 256, 0, stream>>>(
        hbuf, W2T, b2, counts, offsets, ntiles, tile_e, tile_i0, yb, hp, p0, p0 == 0 ? 1 : 0);
  }
  combine_kernel<<<NTOK, 256, 0, stream>>>(yb, tok_ep, pair_w, offsets, out);
}

// Round 7
// 800.167 us; speedup vs baseline: 1.1464x; 1.1464x over previous
//
#include <hip/hip_runtime.h>

typedef unsigned short u16;
typedef __attribute__((ext_vector_type(8))) short bf16x8;
typedef __attribute__((ext_vector_type(8))) unsigned short u16x8;
typedef __attribute__((ext_vector_type(4))) float f32x4;

#define NTOK 8192
#define DDIM 1024
#define HDIM 4096
#define NEXP 8
#define NTILE 136   // 8 XCD chunks x 17 slots; >= max Sum(ceil(cnt_e/128)) = 135
#define GTOK 64     // tokens per gate block

typedef __attribute__((address_space(1))) const void gvoid;
typedef __attribute__((address_space(3))) void lvoid;

__device__ __forceinline__ u16 f2b(float f) {
  unsigned u = __float_as_uint(f);
  u += 0x7fffu + ((u >> 16) & 1u);   // RNE
  return (u16)(u >> 16);
}
__device__ __forceinline__ void glds16(const void* g, void* l) {
  __builtin_amdgcn_global_load_lds((gvoid*)g, (lvoid*)l, 16, 0, 0);
}

// ---------------- pre-pass: [R][C] fp32 -> [C][R] bf16 (per expert) ---------
__global__ void transpose_kernel(const float* __restrict__ src, u16* __restrict__ dst,
                                 int R, int C) {
  int e = blockIdx.z;
  src += (size_t)e * R * C;
  dst += (size_t)e * R * C;
  int r0 = blockIdx.y * 64, c0 = blockIdx.x * 64;
  __shared__ u16 T[64][68];   // row stride 136 B: 8B-aligned, 2-way bank alias (free)
  int t = threadIdx.x;
  int rr = t >> 4, cc = (t & 15) * 4;
#pragma unroll
  for (int i = 0; i < 4; ++i) {
    int r = i * 16 + rr;
    float4 v = *(const float4*)(src + (size_t)(r0 + r) * C + c0 + cc);
    T[cc + 0][r] = f2b(v.x);
    T[cc + 1][r] = f2b(v.y);
    T[cc + 2][r] = f2b(v.z);
    T[cc + 3][r] = f2b(v.w);
  }
  __syncthreads();
#pragma unroll
  for (int i = 0; i < 4; ++i) {
    int c = i * 16 + rr;
    ushort4 o = *(const ushort4*)&T[c][cc];
    *(ushort4*)(dst + (size_t)(c0 + c) * R + r0 + cc) = o;
  }
}

// ---------------- gating: top-2 + fused x->bf16, batched atomics ------------
// 128 blocks x 64 tokens. Positions claimed via LDS atomics; ONE global
// atomicAdd per (block, expert) -> per-expert chains of 128 instead of 2048.
__global__ __launch_bounds__(256) void gate_kernel(
    const float* __restrict__ x, const float* __restrict__ Wg,
    const float* __restrict__ bg, int* __restrict__ counts_pad,
    int* __restrict__ pair_tok, float* __restrict__ pair_w,
    int* __restrict__ tok_ep, u16* __restrict__ xb)
{
  __shared__ int lcnt[NEXP];
  __shared__ int lbase[NEXP];
  __shared__ u16 ent_e[GTOK * 2];
  __shared__ u16 ent_pos[GTOK * 2];
  __shared__ float ent_w[GTOK * 2];

  int t = threadIdx.x;
  if (t < NEXP) lcnt[t] = 0;
  __syncthreads();

  int lane = t & 63;
  int wave = t >> 6;

  for (int it = 0; it < 16; ++it) {
    int ti = wave * 16 + it;
    int tok = blockIdx.x * GTOK + ti;
    const float* xr = x + (size_t)tok * DDIM + lane * 16;
    float xv[16];
#pragma unroll
    for (int j = 0; j < 16; ++j) xv[j] = xr[j];
    // fused convert: x -> bf16
    u16x8 o0, o1;
#pragma unroll
    for (int j = 0; j < 8; ++j) { o0[j] = f2b(xv[j]); o1[j] = f2b(xv[j + 8]); }
    u16* xo = xb + (size_t)tok * DDIM + lane * 16;
    *(u16x8*)(xo) = o0;
    *(u16x8*)(xo + 8) = o1;

    float acc[NEXP];
#pragma unroll
    for (int e = 0; e < NEXP; ++e) acc[e] = 0.f;
#pragma unroll
    for (int j = 0; j < 16; ++j) {
      float xf = xv[j];
      const float* wr = Wg + (size_t)(lane * 16 + j) * NEXP;
      float4 wa = *(const float4*)(wr);
      float4 wb = *(const float4*)(wr + 4);
      acc[0] = fmaf(xf, wa.x, acc[0]);
      acc[1] = fmaf(xf, wa.y, acc[1]);
      acc[2] = fmaf(xf, wa.z, acc[2]);
      acc[3] = fmaf(xf, wa.w, acc[3]);
      acc[4] = fmaf(xf, wb.x, acc[4]);
      acc[5] = fmaf(xf, wb.y, acc[5]);
      acc[6] = fmaf(xf, wb.z, acc[6]);
      acc[7] = fmaf(xf, wb.w, acc[7]);
    }
#pragma unroll
    for (int off = 32; off > 0; off >>= 1) {
#pragma unroll
      for (int e = 0; e < NEXP; ++e) acc[e] += __shfl_xor(acc[e], off, 64);
    }
    if (lane == 0) {
      float l[NEXP];
      float mx = -3.4e38f;
#pragma unroll
      for (int e = 0; e < NEXP; ++e) { l[e] = acc[e] + bg[e]; mx = fmaxf(mx, l[e]); }
      float s = 0.f;
#pragma unroll
      for (int e = 0; e < NEXP; ++e) { l[e] = __expf(l[e] - mx); s += l[e]; }
      float inv = 1.f / s;
      float v1 = -1.f; int i1 = 0;
#pragma unroll
      for (int e = 0; e < NEXP; ++e) { if (l[e] > v1) { v1 = l[e]; i1 = e; } }
      float v2 = -1.f; int i2 = 0;
#pragma unroll
      for (int e = 0; e < NEXP; ++e) { if (e != i1 && l[e] > v2) { v2 = l[e]; i2 = e; } }
      int p1 = atomicAdd(&lcnt[i1], 1);
      ent_e[2 * ti] = (u16)i1; ent_pos[2 * ti] = (u16)p1; ent_w[2 * ti] = v1 * inv;
      int p2 = atomicAdd(&lcnt[i2], 1);
      ent_e[2 * ti + 1] = (u16)i2; ent_pos[2 * ti + 1] = (u16)p2; ent_w[2 * ti + 1] = v2 * inv;
    }
  }
  __syncthreads();
  if (t < NEXP) lbase[t] = atomicAdd(&counts_pad[t * 32], lcnt[t]);
  __syncthreads();
  if (t < GTOK * 2) {
    int e = ent_e[t];
    int p = lbase[e] + ent_pos[t];
    int tok = blockIdx.x * GTOK + (t >> 1);
    pair_tok[e * NTOK + p] = tok;
    pair_w[e * NTOK + p] = ent_w[t];    // raw top-k softmax prob (not renormalized)
    tok_ep[2 * tok + (t & 1)] = (e << 16) | p;
  }
}

// ---------------- offsets + XCD-chunked worklist (LDS only, no scratch) -----
// Grid slot w -> expert-major tile (w%8)*17 + w/8, so XCD c (= w%8) processes
// 17 CONTIGUOUS expert-major tiles (~one expert) -> B-slab stays in its L2.
__global__ void offsets_kernel(const int* __restrict__ counts_pad, int* __restrict__ counts,
                               int* __restrict__ offsets, int* __restrict__ tile_e,
                               int* __restrict__ tile_i0, int* __restrict__ ntiles)
{
  __shared__ int cumt[NEXP + 1];
  int t = threadIdx.x;
  if (t == 0) {
    int s = 0, ct = 0;
    for (int e = 0; e < NEXP; ++e) {
      int c = counts_pad[e * 32];
      counts[e] = c; offsets[e] = s; s += c;
      cumt[e] = ct; ct += (c + 127) >> 7;
    }
    cumt[NEXP] = ct;
    *ntiles = ct;
  }
  __syncthreads();
  if (t < NTILE) {
    int tt = (t & 7) * 17 + (t >> 3);
    int ntot = cumt[NEXP];
    int e = -1, i0 = 0;
    if (tt < ntot) {
#pragma unroll
      for (int e2 = 0; e2 < NEXP; ++e2)
        if (tt >= cumt[e2] && tt < cumt[e2 + 1]) { e = e2; i0 = (tt - cumt[e2]) << 7; }
    }
    tile_e[t] = e;
    tile_i0[t] = i0;
  }
}

// ---------------- shared GEMM helpers (128x128 tile, BK=32, 4 waves) --------
__device__ __forceinline__ void stage4(const u16* xa0, const u16* xa1,
                                       const u16* wb0, const u16* wb1,
                                       u16* Asb, u16* Bsb, int wave, int koff) {
  glds16(xa0 + koff, Asb + wave * 512);
  glds16(xa1 + koff, Asb + 2048 + wave * 512);
  glds16(wb0 + koff, Bsb + wave * 512);
  glds16(wb1 + koff, Bsb + 2048 + wave * 512);
}

__device__ __forceinline__ void mfma_tile(const u16* Asb, const u16* Bsb,
                                          f32x4 (&acc)[4][4],
                                          int wrr, int wc, int ln, int q) {
  bf16x8 af[4], bfr[4];
#pragma unroll
  for (int mt = 0; mt < 4; ++mt)
    af[mt] = *(const bf16x8*)(Asb + (wrr + mt * 16 + ln) * 32 + q * 8);
#pragma unroll
  for (int nt = 0; nt < 4; ++nt)
    bfr[nt] = *(const bf16x8*)(Bsb + (wc + nt * 16 + ln) * 32 + q * 8);
#pragma unroll
  for (int mt = 0; mt < 4; ++mt)
#pragma unroll
    for (int nt = 0; nt < 4; ++nt)
      acc[mt][nt] = __builtin_amdgcn_mfma_f32_16x16x32_bf16(af[mt], bfr[nt], acc[mt][nt], 0, 0, 0);
}

// 3-deep counted-vmcnt K-loop (T4-lite): loads for buffer k+1/k+2 stay in
// flight across the barrier; steady-state wait is vmcnt(4), never 0.
#define GEMM_LOOP(KDIM)                                                      \
  stage4(xa0, xa1, wb0, wb1, As[0], Bs[0], wave, 0);                         \
  stage4(xa0, xa1, wb0, wb1, As[1], Bs[1], wave, 32);                        \
  {                                                                          \
    int cur = 0, nx2 = 2;                                                    \
    for (int k0 = 0; k0 < (KDIM); k0 += 32) {                                \
      __builtin_amdgcn_sched_barrier(0);                                     \
      if (k0 + 32 < (KDIM))                                                  \
        asm volatile("s_waitcnt vmcnt(4) lgkmcnt(0)" ::: "memory");          \
      else                                                                   \
        asm volatile("s_waitcnt vmcnt(0) lgkmcnt(0)" ::: "memory");          \
      __builtin_amdgcn_s_barrier();                                          \
      __builtin_amdgcn_sched_barrier(0);                                     \
      if (k0 + 64 < (KDIM))                                                  \
        stage4(xa0, xa1, wb0, wb1, As[nx2], Bs[nx2], wave, k0 + 64);         \
      mfma_tile(As[cur], Bs[cur], acc, wrr, wc, ln, q);                      \
      cur = (cur == 2) ? 0 : cur + 1;                                        \
      nx2 = (nx2 == 2) ? 0 : nx2 + 1;                                        \
    }                                                                        \
  }

// ---------------- grouped GEMM1: h = relu(gather(xb) @ W1T[e]^T + b1[e]) ----
__global__ __launch_bounds__(256) void gemm1_kernel(
    const u16* __restrict__ xb, const u16* __restrict__ W1T,
    const float* __restrict__ b1, const int* __restrict__ counts,
    const int* __restrict__ offsets, const int* __restrict__ ntiles,
    const int* __restrict__ tile_e, const int* __restrict__ tile_i0,
    const int* __restrict__ pair_tok, u16* __restrict__ h, int hp, int p0)
{
  int bx = blockIdx.x;
  int e = tile_e[bx];
  if (e < 0) return;
  int i0 = tile_i0[bx];
  int cnt = counts[e];
  int n0 = blockIdx.y * 128;

  __shared__ __align__(16) u16 As[3][4096];
  __shared__ __align__(16) u16 Bs[3][4096];

  int t = threadIdx.x;
  int lane = t & 63;
  int wave = t >> 6;
  int rlim = cnt - i0;
  int rl = rlim - 1;

  const int* tokp = pair_tok + e * NTOK + i0;
  int arow = t >> 2;
  int c8 = (t & 3) * 8;
  const u16* xa0 = xb + (size_t)tokp[min(arow, rl)] * DDIM + c8;
  const u16* xa1 = xb + (size_t)tokp[min(arow + 64, rl)] * DDIM + c8;
  const u16* wb0 = W1T + (size_t)e * HDIM * DDIM + (size_t)(p0 + n0 + arow) * DDIM + c8;
  const u16* wb1 = wb0 + (size_t)64 * DDIM;

  f32x4 acc[4][4] = {};
  int wrr = (wave >> 1) * 64;
  int wc = (wave & 1) * 64;
  int ln = lane & 15;
  int q = lane >> 4;

  GEMM_LOOP(DDIM);

  int ob = offsets[e];
  float bb[4];
#pragma unroll
  for (int nt = 0; nt < 4; ++nt)
    bb[nt] = b1[(size_t)e * HDIM + p0 + n0 + wc + nt * 16 + ln];
  size_t hbase = (size_t)(ob + i0) * hp + n0 + wc;
#pragma unroll
  for (int mt = 0; mt < 4; ++mt) {
#pragma unroll
    for (int r = 0; r < 4; ++r) {
      int row = wrr + mt * 16 + q * 4 + r;
      if (row < rlim) {
        u16* hrow = h + hbase + (size_t)row * hp;
#pragma unroll
        for (int nt = 0; nt < 4; ++nt) {
          float v = acc[mt][nt][r] + bb[nt];
          hrow[nt * 16 + ln] = f2b(fmaxf(v, 0.f));
        }
      }
    }
  }
}

// ---------------- grouped GEMM2: y[slot] (+)= h @ W2T[e]^T (+ b2[e]) --------
__global__ __launch_bounds__(256) void gemm2_kernel(
    const u16* __restrict__ h, const u16* __restrict__ W2T,
    const float* __restrict__ b2v, const int* __restrict__ counts,
    const int* __restrict__ offsets, const int* __restrict__ ntiles,
    const int* __restrict__ tile_e, const int* __restrict__ tile_i0,
    float* __restrict__ y, int hp, int p0, int first)
{
  int bx = blockIdx.x;
  int e = tile_e[bx];
  if (e < 0) return;
  int i0 = tile_i0[bx];
  int cnt = counts[e];
  int n0 = blockIdx.y * 128;

  __shared__ __align__(16) u16 As[3][4096];
  __shared__ __align__(16) u16 Bs[3][4096];

  int t = threadIdx.x;
  int lane = t & 63;
  int wave = t >> 6;
  int rlim = cnt - i0;
  int rl = rlim - 1;
  int rbase = offsets[e] + i0;

  int arow = t >> 2;
  int c8 = (t & 3) * 8;
  const u16* xa0 = h + (size_t)(rbase + min(arow, rl)) * hp + c8;
  const u16* xa1 = h + (size_t)(rbase + min(arow + 64, rl)) * hp + c8;
  const u16* wb0 = W2T + (size_t)e * DDIM * HDIM + (size_t)(n0 + arow) * HDIM + p0 + c8;
  const u16* wb1 = wb0 + (size_t)64 * HDIM;

  f32x4 acc[4][4] = {};
  int wrr = (wave >> 1) * 64;
  int wc = (wave & 1) * 64;
  int ln = lane & 15;
  int q = lane >> 4;

  GEMM_LOOP(hp);

  float bb[4];
#pragma unroll
  for (int nt = 0; nt < 4; ++nt)
    bb[nt] = first ? b2v[(size_t)e * DDIM + n0 + wc + nt * 16 + ln] : 0.f;
#pragma unroll
  for (int mt = 0; mt < 4; ++mt) {
#pragma unroll
    for (int r = 0; r < 4; ++r) {
      int row = wrr + mt * 16 + q * 4 + r;
      if (row < rlim) {
        float* yr = y + (size_t)(rbase + row) * DDIM + n0 + wc;
#pragma unroll
        for (int nt = 0; nt < 4; ++nt) {
          float v = acc[mt][nt][r] + bb[nt];
          if (first) yr[nt * 16 + ln] = v;
          else       yr[nt * 16 + ln] += v;
        }
      }
    }
  }
}

// ---------------- combine: out[tok] = w1*y[slot1] + w2*y[slot2] -------------
__global__ __launch_bounds__(256) void combine_kernel(
    const float* __restrict__ y, const int* __restrict__ tok_ep,
    const float* __restrict__ pair_w, const int* __restrict__ offsets,
    float* __restrict__ out)
{
  int tok = blockIdx.x;
  int ep1 = tok_ep[2 * tok + 0];
  int ep2 = tok_ep[2 * tok + 1];
  int e1 = ep1 >> 16, p1 = ep1 & 0xffff;
  int e2 = ep2 >> 16, p2 = ep2 & 0xffff;
  float w1 = pair_w[e1 * NTOK + p1];
  float w2 = pair_w[e2 * NTOK + p2];
  const float* r1 = y + (size_t)(offsets[e1] + p1) * DDIM;
  const float* r2 = y + (size_t)(offsets[e2] + p2) * DDIM;
  int c = threadIdx.x * 4;
  float4 a = *(const float4*)(r1 + c);
  float4 b = *(const float4*)(r2 + c);
  float4 o;
  o.x = w1 * a.x + w2 * b.x;
  o.y = w1 * a.y + w2 * b.y;
  o.z = w1 * a.z + w2 * b.z;
  o.w = w1 * a.w + w2 * b.w;
  *(float4*)(out + (size_t)tok * DDIM + c) = o;
}

// ---------------- host launch ------------------------------------------------
extern "C" void kernel_launch(void* const* d_in, const int* in_sizes, int n_in,
                              void* d_out, int out_size, void* d_ws, size_t ws_size,
                              hipStream_t stream)
{
  const float* x  = (const float*)d_in[0];
  const float* Wg = (const float*)d_in[1];
  const float* bg = (const float*)d_in[2];
  const float* W1 = (const float*)d_in[3];
  const float* b1 = (const float*)d_in[4];
  const float* W2 = (const float*)d_in[5];
  const float* b2 = (const float*)d_in[6];
  float* out = (float*)d_out;

  char* ws = (char*)d_ws;
  int*   counts_pad = (int*)(ws + 0);                      // 8 counters, 128B apart
  int*   counts     = (int*)(ws + 1024);
  int*   offsets    = (int*)(ws + 1056);
  int*   ntiles     = (int*)(ws + 1088);
  int*   tile_e     = (int*)(ws + 1152);                   // NTILE entries
  int*   tile_i0    = (int*)(ws + 2176);
  int*   tok_ep     = (int*)(ws + 4096);                   // 64 KiB
  int*   pair_tok   = (int*)(ws + 69632);                  // 256 KiB
  float* pair_w     = (float*)(ws + 331776);               // 256 KiB
  u16*   xb  = (u16*)(ws + 593920);                                // 16.78 MB
  u16*   W1T = (u16*)(ws + 593920 + 16777216);                     // 67.1 MB
  u16*   W2T = (u16*)(ws + 593920 + 16777216 + 67108864);          // 67.1 MB
  float* yb  = (float*)(ws + 593920 + 16777216 + 2 * (size_t)67108864);
  u16*   hbuf = (u16*)(ws + 593920 + 16777216 + 3 * (size_t)67108864);
  size_t used_base = 593920 + 16777216 + 3 * (size_t)67108864;

  // largest H-phase width whose h buffer ((16384+128) rows x hp bf16) fits in ws
  int hp = 256;
  const int cands[5] = {4096, 2048, 1024, 512, 256};
  for (int ci = 0; ci < 5; ++ci) {
    if (used_base + (size_t)16512 * cands[ci] * 2 <= ws_size) { hp = cands[ci]; break; }
  }

  hipMemsetAsync(counts_pad, 0, 1024, stream);
  // W1 [E][D][H] -> W1T [E][H][D]
  transpose_kernel<<<dim3(HDIM / 64, DDIM / 64, NEXP), 256, 0, stream>>>(W1, W1T, DDIM, HDIM);
  // W2 [E][H][D] -> W2T [E][D][H]
  transpose_kernel<<<dim3(DDIM / 64, HDIM / 64, NEXP), 256, 0, stream>>>(W2, W2T, HDIM, DDIM);
  gate_kernel<<<NTOK / GTOK, 256, 0, stream>>>(x, Wg, bg, counts_pad, pair_tok, pair_w,
                                               tok_ep, xb);
  offsets_kernel<<<1, 256, 0, stream>>>(counts_pad, counts, offsets, tile_e, tile_i0, ntiles);
  for (int p0 = 0; p0 < HDIM; p0 += hp) {
    gemm1_kernel<<<dim3(NTILE, hp / 128), 256, 0, stream>>>(
        xb, W1T, b1, counts, offsets, ntiles, tile_e, tile_i0, pair_tok, hbuf, hp, p0);
    gemm2_kernel<<<dim3(NTILE, DDIM / 128), 256, 0, stream>>>(
        hbuf, W2T, b2, counts, offsets, ntiles, tile_e, tile_i0, yb, hp, p0, p0 == 0 ? 1 : 0);
  }
  combine_kernel<<<NTOK, 256, 0, stream>>>(yb, tok_ep, pair_w, offsets, out);
}